// Round 17
// baseline (12.918 us; speedup 1.0000x reference)
//
#include <hip/hip_runtime.h>

#define NQ 10
#define NR 8               // amplitudes per lane (2^3)

// TWO WAVES per batch element (r17). Flat index k = wv*512 + lane*8 + r:
//   bit 9 = wv, bits 8..3 = lane bits L5..L0, bits 2..0 = reg bits r2..r0.
// r13's verified spectral form: psi = W . diag(e^{-i phi}) . W . psi_init,
// re-derived for the split layout:
//  * j^-T bits (r13-verified formulas, raw k-bits): bit_c = (k0^..^kc)^k9
//    (c<=8), bit_9 = k0^..^k8. Qubit q reads bit (9-q):
//      q0: rq3^PL5          q1..q6: rq3^PL{5..1,0}^wv   q7: rq3^wv
//      q8: (r0^r1)^wv       q9: r0^wv        (rq3 = r0^r1^r2)
//    -> A[t=rq3] = prod q=0..7; G[t2=r0^r1][t1=r0] = f8*f9.
//  * phi via 8-pt WHT of C[8] (30 masks from r12 re-split: wv-bit -> sw sign,
//    k-bits 8..3 -> lane mask, k-bits 2..0 -> reg index).
//  * W#2: 3 reg levels + 6 lane levels (DS impls, r13-verified) + ONE
//    cross-wave LDS exchange (the k9 butterfly level).
//  * readout masks re-split likewise; cross-wave z-sum via small LDS buffer.
// 4096 waves -> 4 waves/SIMD (vs 2): 2x TLP for latency hiding.

__device__ __forceinline__ float xf(int i) { return __int_as_float(i); }
__device__ __forceinline__ int   fx(float f) { return __float_as_int(f); }

template<int M>
__device__ __forceinline__ float lane_xor(float v, int a32) {
    if constexpr (M == 1)        // quad_perm [1,0,3,2]
        return xf(__builtin_amdgcn_update_dpp(fx(v), fx(v), 0xB1, 0xF, 0xF, true));
    else if constexpr (M == 2)   // quad_perm [2,3,0,1]
        return xf(__builtin_amdgcn_update_dpp(fx(v), fx(v), 0x4E, 0xF, 0xF, true));
    else if constexpr (M == 8)   // row_ror:8
        return xf(__builtin_amdgcn_update_dpp(fx(v), fx(v), 0x128, 0xF, 0xF, true));
    else if constexpr (M == 4)   // ds_swizzle bit-mode xor 4
        return xf(__builtin_amdgcn_ds_swizzle(fx(v), 0x101F));
    else if constexpr (M == 16)  // ds_swizzle bit-mode xor 16
        return xf(__builtin_amdgcn_ds_swizzle(fx(v), 0x401F));
    else                         // M == 32: bpermute
        return xf(__builtin_amdgcn_ds_bpermute(a32, fx(v)));
}

__global__ __launch_bounds__(256, 4) void vql_kernel(
    const float* __restrict__ x,     // (B, NQ)
    const float* __restrict__ w,     // (NDEPTH, NQ)
    float* __restrict__ out)         // (B, NQ)
{
    __shared__ float4 xch[2][2][4][64];   // [elem][wv][quad][lane] = 16 KB
    __shared__ float  zbuf[2][2][NQ];

    const int tid  = threadIdx.x;
    const int lane = tid & 63;
    const int wv   = (tid >> 6) & 1;
    const int eb   = tid >> 7;            // element within block (0/1)
    const int b    = blockIdx.x * 2 + eb;
    const int a32  = (lane ^ 32) << 2;

    // ---- per-batch angles (vectorized) ----
    const float2* xr = reinterpret_cast<const float2*>(x + b * NQ);
    const float2 x01 = xr[0], x23 = xr[1], x45 = xr[2], x67 = xr[3], x89 = xr[4];
    const float xa[NQ] = {0.5f * x01.x, 0.5f * x01.y, 0.5f * x23.x, 0.5f * x23.y,
                          0.5f * x45.x, 0.5f * x45.y, 0.5f * x67.x, 0.5f * x67.y,
                          0.5f * x89.x, 0.5f * x89.y};

    // ---- per-qubit Walsh factors f'(t) = f(0) +- f(1) of RX(w0q)RY(xq)|0> ----
    float F0r[NQ], F0i[NQ], F1r[NQ], F1i[NQ];
    #pragma unroll
    for (int q = 0; q < NQ; ++q) {
        float sy, cy, s, c;
        __sincosf(xa[q], &sy, &cy);
        __sincosf(0.5f * w[q], &s, &c);   // layer-0 weights
        const float v0r = c * cy,  v0i = -s * sy;
        const float v1r = c * sy,  v1i = -s * cy;
        F0r[q] = v0r + v1r;  F0i[q] = v0i + v1i;
        F1r[q] = v0r - v1r;  F1i[q] = v0i - v1i;
    }

    // ---- psi1 = W psi_init (j^-T product construction, split layout) ----
    const int L0 = lane & 1,        L1 = (lane >> 1) & 1, L2 = (lane >> 2) & 1;
    const int L3 = (lane >> 3) & 1, L4 = (lane >> 4) & 1, L5 = (lane >> 5) & 1;
    const int PL1 = L0 ^ L1, PL2 = PL1 ^ L2, PL3 = PL2 ^ L3, PL4 = PL3 ^ L4, PL5 = PL4 ^ L5;
    const int gb[8] = {PL5, PL5 ^ wv, PL4 ^ wv, PL3 ^ wv, PL2 ^ wv, PL1 ^ wv, L0 ^ wv, wv};
    #define SR_(q,bit) ((bit) ? F1r[q] : F0r[q])
    #define SI_(q,bit) ((bit) ? F1i[q] : F0i[q])

    float A_r[2], A_i[2];                 // prod q=0..7, indexed by t = rq3
    #pragma unroll
    for (int t = 0; t < 2; ++t) {
        float ar = SR_(0, gb[0] ^ t), ai = SI_(0, gb[0] ^ t);
        #pragma unroll
        for (int q = 1; q < 8; ++q) {
            const float br = SR_(q, gb[q] ^ t), bi = SI_(q, gb[q] ^ t);
            const float nr = ar * br - ai * bi;
            const float ni = ar * bi + ai * br;
            ar = nr; ai = ni;
        }
        A_r[t] = ar * (1.0f / 1024.0f);   // fold W.W normalization
        A_i[t] = ai * (1.0f / 1024.0f);
    }
    float Gr[2][2], Gi[2][2];             // f8(t2^wv) * f9(t1^wv)
    #pragma unroll
    for (int t2 = 0; t2 < 2; ++t2)
        #pragma unroll
        for (int t1 = 0; t1 < 2; ++t1) {
            const float ar = SR_(8, t2 ^ wv), ai = SI_(8, t2 ^ wv);
            const float br = SR_(9, t1 ^ wv), bi = SI_(9, t1 ^ wv);
            Gr[t2][t1] = ar * br - ai * bi;
            Gi[t2][t1] = ar * bi + ai * br;
        }
    float re[NR], im[NR];
    #pragma unroll
    for (int r = 0; r < NR; ++r) {
        const int r0 = r & 1, r1 = (r >> 1) & 1, r2 = (r >> 2) & 1;
        const int rp2 = r0 ^ r1, rq3 = rp2 ^ r2;
        const float gr = Gr[rp2][r0], gi = Gi[rp2][r0];
        re[r] = A_r[rq3] * gr - A_i[rq3] * gi;
        im[r] = A_r[rq3] * gi + A_i[rq3] * gr;
    }
    #undef SR_
    #undef SI_

    // ---- diagonal phases: phi[r] via 8-pt WHT of lane/wv-signed coeffs ----
    float h1[NQ], h2[NQ], h3[NQ];
    #pragma unroll
    for (int q = 0; q < NQ; ++q) {
        h1[q] = 0.5f * w[NQ + q];
        h2[q] = 0.5f * w[2 * NQ + q];
        h3[q] = 0.5f * w[3 * NQ + q];
    }
    #define SG_(M) ((__builtin_popcount(lane & (M)) & 1) ? -1.f : 1.f)
    const float g1 = SG_(1),  g2 = SG_(2),  g3 = SG_(3),  g4 = SG_(4),  g5 = SG_(5);
    const float g6 = SG_(6),  g8 = SG_(8),  g10 = SG_(10), g12 = SG_(12);
    const float g16 = SG_(16), g20 = SG_(20), g24 = SG_(24), g32 = SG_(32);
    const float g40 = SG_(40), g48 = SG_(48);
    const float sw = wv ? -1.f : 1.f;

    float C[NR];
    C[0] = sw * h1[0] + g32 * h1[1] + g16 * h1[2] + g8 * h1[3] + g4 * h1[4]
         + g2 * h1[5] + g1 * h1[6]
         + sw * g32 * h2[0] + g48 * h2[1] + g24 * h2[2] + g12 * h2[3]
         + g6 * h2[4] + g3 * h2[5]
         + sw * g16 * h3[0] + g40 * h3[1] + g20 * h3[2] + g10 * h3[3] + g5 * h3[4];
    C[4] = h1[7] + g1 * h2[6] + g2 * h3[5];
    C[2] = h1[8] + g1 * h3[6] + sw * g32 * h3[8];
    C[1] = h1[9] + sw * g32 * h2[9] + g48 * h3[9];
    C[6] = h2[7];
    C[3] = h2[8];
    C[5] = h3[7];
    C[7] = 0.f;

    #pragma unroll
    for (int bset = 0; bset < 3; ++bset) {      // 8-pt WHT: C -> phi
        const int bb = 1 << bset;
        #pragma unroll
        for (int r = 0; r < NR; ++r) {
            if (!(r & bb)) {
                const float u = C[r], v = C[r | bb];
                C[r] = u + v;  C[r | bb] = u - v;
            }
        }
    }
    #pragma unroll
    for (int r = 0; r < NR; ++r) {              // apply e^{-i phi}
        float sp, cp;
        __sincosf(C[r], &sp, &cp);
        const float nr = re[r] * cp + im[r] * sp;
        const float ni = im[r] * cp - re[r] * sp;
        re[r] = nr; im[r] = ni;
    }

    // ---- W#2: 3 reg levels + 6 lane levels + 1 wave level ----
    #pragma unroll
    for (int bset = 0; bset < 3; ++bset) {
        const int bb = 1 << bset;
        #pragma unroll
        for (int r = 0; r < NR; ++r) {
            if (!(r & bb)) {
                float u = re[r], v = re[r | bb];
                re[r] = u + v;  re[r | bb] = u - v;
                u = im[r]; v = im[r | bb];
                im[r] = u + v;  im[r | bb] = u - v;
            }
        }
    }
    {
        const float sgA = (lane &  1) ? -1.f : 1.f;
        const float sgB = (lane &  2) ? -1.f : 1.f;
        const float sgC = (lane &  4) ? -1.f : 1.f;
        const float sgD = (lane &  8) ? -1.f : 1.f;
        const float sgE = (lane & 16) ? -1.f : 1.f;
        const float sgF = (lane & 32) ? -1.f : 1.f;
        #pragma unroll
        for (int r = 0; r < NR; ++r) {
            float p;
            p = lane_xor< 1>(re[r], a32); re[r] = fmaf(sgA, re[r], p);
            p = lane_xor< 1>(im[r], a32); im[r] = fmaf(sgA, im[r], p);
            p = lane_xor< 2>(re[r], a32); re[r] = fmaf(sgB, re[r], p);
            p = lane_xor< 2>(im[r], a32); im[r] = fmaf(sgB, im[r], p);
            p = lane_xor< 4>(re[r], a32); re[r] = fmaf(sgC, re[r], p);
            p = lane_xor< 4>(im[r], a32); im[r] = fmaf(sgC, im[r], p);
            p = lane_xor< 8>(re[r], a32); re[r] = fmaf(sgD, re[r], p);
            p = lane_xor< 8>(im[r], a32); im[r] = fmaf(sgD, im[r], p);
            p = lane_xor<16>(re[r], a32); re[r] = fmaf(sgE, re[r], p);
            p = lane_xor<16>(im[r], a32); im[r] = fmaf(sgE, im[r], p);
            p = lane_xor<32>(re[r], a32); re[r] = fmaf(sgF, re[r], p);
            p = lane_xor<32>(im[r], a32); im[r] = fmaf(sgF, im[r], p);
        }
    }
    // wave level: exchange all 16 floats with the partner wave via LDS
    xch[eb][wv][0][lane] = make_float4(re[0], re[1], re[2], re[3]);
    xch[eb][wv][1][lane] = make_float4(re[4], re[5], re[6], re[7]);
    xch[eb][wv][2][lane] = make_float4(im[0], im[1], im[2], im[3]);
    xch[eb][wv][3][lane] = make_float4(im[4], im[5], im[6], im[7]);
    __syncthreads();
    {
        const float4 pr0 = xch[eb][wv ^ 1][0][lane], pr1 = xch[eb][wv ^ 1][1][lane];
        const float4 pi0 = xch[eb][wv ^ 1][2][lane], pi1 = xch[eb][wv ^ 1][3][lane];
        const float prre[NR] = {pr0.x, pr0.y, pr0.z, pr0.w, pr1.x, pr1.y, pr1.z, pr1.w};
        const float prim[NR] = {pi0.x, pi0.y, pi0.z, pi0.w, pi1.x, pi1.y, pi1.z, pi1.w};
        const float sgW = wv ? -1.f : 1.f;
        #pragma unroll
        for (int r = 0; r < NR; ++r) {
            re[r] = fmaf(sgW, re[r], prre[r]);
            im[r] = fmaf(sgW, im[r], prim[r]);
        }
    }

    // ---- readout: probs -> 8-pt reg WHT -> parity-signed observables ----
    float P[NR];
    #pragma unroll
    for (int r = 0; r < NR; ++r) P[r] = re[r] * re[r] + im[r] * im[r];
    #pragma unroll
    for (int bset = 0; bset < 3; ++bset) {
        const int bb = 1 << bset;
        #pragma unroll
        for (int r = 0; r < NR; ++r) {
            if (!(r & bb)) {
                const float u = P[r], v = P[r | bb];
                P[r] = u + v;  P[r | bb] = u - v;
            }
        }
    }
    const float q25 = SG_(25), q53 = SG_(53), q26 = SG_(26), q13 = SG_(13);
    const float q38 = SG_(38), q51 = SG_(51), q12 = SG_(12);
    #undef SG_

    float z[NQ];
    z[0] = sw * q25 * P[4];
    z[1] = q53 * P[2];
    z[2] = q26 * P[5];
    z[3] = sw * q13 * P[2];
    z[4] = sw * q38 * P[5];
    z[5] = q51 * P[2];
    z[6] = q25 * P[5];
    z[7] = sw * q12 * P[6];
    z[8] = sw * q38 * P[3];
    z[9] = q51 * P[1];

    #pragma unroll
    for (int q = 0; q < NQ; ++q) {
        z[q] += lane_xor< 1>(z[q], a32);
        z[q] += lane_xor< 2>(z[q], a32);
        z[q] += lane_xor< 4>(z[q], a32);
        z[q] += lane_xor< 8>(z[q], a32);
        z[q] += lane_xor<16>(z[q], a32);
        z[q] += lane_xor<32>(z[q], a32);
    }
    if (lane == 0) {
        #pragma unroll
        for (int q = 0; q < NQ; ++q) zbuf[eb][wv][q] = z[q];
    }
    __syncthreads();
    if (wv == 0 && lane == 0) {
        #pragma unroll
        for (int q = 0; q < NQ; ++q) out[b * NQ + q] = z[q] + zbuf[eb][1][q];
    }
}

extern "C" void kernel_launch(void* const* d_in, const int* in_sizes, int n_in,
                              void* d_out, int out_size, void* d_ws, size_t ws_size,
                              hipStream_t stream) {
    const float* x = (const float*)d_in[0];        // (BATCH, NQ) fp32
    const float* w = (const float*)d_in[1];        // (NDEPTH, NQ) fp32
    float* out = (float*)d_out;                    // (BATCH, NQ) fp32
    const int B = in_sizes[0] / NQ;                // 2048
    vql_kernel<<<B / 2, 256, 0, stream>>>(x, w, out);
}